// Round 2
// baseline (249.355 us; speedup 1.0000x reference)
//
#include <hip/hip_runtime.h>
#include <hip/hip_bf16.h>
#include <cstddef>

// percnn time stepping, fused single kernel.
//
// Every conv is 1x1, so each output pixel is a pure function of the scalars
// (u,v) at that pixel; each branch collapses to a bivariate cubic. Instead of
// a separate 1-workgroup coefficient kernel (serialized in the graph, leaves
// 255 CUs idle), EVERY block redundantly computes the 20 monomial
// coefficients (~1000 FLOPs, weights are L2/L3-resident) into LDS, then
// streams pixels: 16 B/pixel HBM traffic, ~30 VALU ops/pixel.
//
// Monomial order m: 0:u^3 1:u^2v 2:uv^2 3:v^3 4:u^2 5:uv 6:v^2 7:u 8:v 9:1
// out0 = u + sum_m c0[m]*mono_m ; out1 = v + sum_m c1[m]*mono_m
// c0 = DT*(S0 + DU*U-branch), c1 = DT*(S1 + DV*V-branch).

#define HIDC 16

struct PercnnW {
    const float* w1u; const float* b1u; const float* w2u; const float* b2u;
    const float* w3u; const float* b3u; const float* w4u; const float* b4u;
    const float* w1v; const float* b1v; const float* w2v; const float* b2v;
    const float* w3v; const float* b3v; const float* w4v; const float* b4v;
    const float* w1s; const float* b1s; const float* w2s; const float* b2s;
    const float* w3s; const float* b3s; const float* w4s; const float* b4s;
};

__global__ __launch_bounds__(256) void percnn_fused_kernel(
    const float* __restrict__ x, PercnnW W, float* __restrict__ out)
{
    // ---- Phase 1: per-block coefficient computation (redundant, cheap) ----
    // part[c][0..9]  = w4s[0][c] * P_c[m]      (s-branch, output 0)
    // part[c][10..19]= w4s[1][c] * P_c[m]      (s-branch, output 1)
    // part[c][20..23]= w4u[c] * {u3,u2,u,1}    (u diffusion branch)
    // part[c][24..27]= w4v[c] * {v3,v2,v,1}    (v diffusion branch)
    __shared__ float part[HIDC][28];
    __shared__ float cws[20];
    const int t = threadIdx.x;
    if (t < HIDC) {
        const int c = t;
        { // u branch: h_i = a_i*u + d_i
            float a1 = W.w1u[c], d1 = W.b1u[c];
            float a2 = W.w2u[c], d2 = W.b2u[c];
            float a3 = W.w3u[c], d3 = W.b3u[c];
            float w4 = W.w4u[c];
            float X2 = a1 * a2;
            float X1 = a1 * d2 + d1 * a2;
            float X0 = d1 * d2;
            part[c][20] = w4 * (X2 * a3);
            part[c][21] = w4 * (X2 * d3 + X1 * a3);
            part[c][22] = w4 * (X1 * d3 + X0 * a3);
            part[c][23] = w4 * (X0 * d3);
        }
        { // v branch
            float a1 = W.w1v[c], d1 = W.b1v[c];
            float a2 = W.w2v[c], d2 = W.b2v[c];
            float a3 = W.w3v[c], d3 = W.b3v[c];
            float w4 = W.w4v[c];
            float X2 = a1 * a2;
            float X1 = a1 * d2 + d1 * a2;
            float X0 = d1 * d2;
            part[c][24] = w4 * (X2 * a3);
            part[c][25] = w4 * (X2 * d3 + X1 * a3);
            part[c][26] = w4 * (X1 * d3 + X0 * a3);
            part[c][27] = w4 * (X0 * d3);
        }
        { // s branch: h_i = a_i*u + c_i*v + d_i
            float a1 = W.w1s[2 * c], c1 = W.w1s[2 * c + 1], d1 = W.b1s[c];
            float a2 = W.w2s[2 * c], c2 = W.w2s[2 * c + 1], d2 = W.b2s[c];
            float a3 = W.w3s[2 * c], c3 = W.w3s[2 * c + 1], d3 = W.b3s[c];
            float w40 = W.w4s[c], w41 = W.w4s[HIDC + c];
            float X2 = a1 * a2;
            float XY = a1 * c2 + c1 * a2;
            float Y2 = c1 * c2;
            float X1 = a1 * d2 + d1 * a2;
            float Y1 = c1 * d2 + d1 * c2;
            float X0 = d1 * d2;
            float P[10];
            P[0] = X2 * a3;                      // u^3
            P[1] = X2 * c3 + XY * a3;            // u^2 v
            P[2] = XY * c3 + Y2 * a3;            // u v^2
            P[3] = Y2 * c3;                      // v^3
            P[4] = X2 * d3 + X1 * a3;            // u^2
            P[5] = XY * d3 + X1 * c3 + Y1 * a3;  // u v
            P[6] = Y2 * d3 + Y1 * c3;            // v^2
            P[7] = X1 * d3 + X0 * a3;            // u
            P[8] = Y1 * d3 + X0 * c3;            // v
            P[9] = X0 * d3;                      // 1
#pragma unroll
            for (int m = 0; m < 10; ++m) {
                part[c][m] = w40 * P[m];
                part[c][10 + m] = w41 * P[m];
            }
        }
    }
    __syncthreads();
    if (t == 0) {
        const float DT = 0.05f, DUc = 0.001f, DVc = 0.005f;
        float red[28];
#pragma unroll
        for (int m = 0; m < 28; ++m) {
            float s = 0.f;
#pragma unroll
            for (int i = 0; i < HIDC; ++i) s += part[i][m];
            red[m] = s;
        }
        float c0[10], c1[10];
#pragma unroll
        for (int m = 0; m < 10; ++m) { c0[m] = red[m]; c1[m] = red[10 + m]; }
        c0[0] += DUc * red[20];
        c0[4] += DUc * red[21];
        c0[7] += DUc * red[22];
        c0[9] += W.b4s[0] + DUc * (red[23] + W.b4u[0]);
        c1[3] += DVc * red[24];
        c1[6] += DVc * red[25];
        c1[8] += DVc * red[26];
        c1[9] += W.b4s[1] + DVc * (red[27] + W.b4v[0]);
#pragma unroll
        for (int m = 0; m < 10; ++m) { cws[m] = DT * c0[m]; cws[10 + m] = DT * c1[m]; }
    }
    __syncthreads();

    // ---- Phase 2: streaming evaluation ----
    float c0[10], c1[10];
#pragma unroll
    for (int i = 0; i < 10; ++i) { c0[i] = cws[i]; c1[i] = cws[10 + i]; }

    const int HW = 512 * 512;          // 262144 pixels per plane
    const unsigned g = blockIdx.x * blockDim.x + t;
    const unsigned b = g >> 16;        // HW/4 = 65536 float4 groups per plane
    const unsigned r4 = g & 65535u;

    const float4 u4 = ((const float4*)(x + (size_t)(4 * b + 2) * HW))[r4];
    const float4 v4 = ((const float4*)(x + (size_t)(4 * b + 3) * HW))[r4];

    float4 o0, o1;
#define EVAL_UV(U, V, O0, O1)                                                  \
    {                                                                          \
        float uu = (U) * (U), vv = (V) * (V), uvp = (U) * (V);                 \
        O0 = (U) + ((c0[0] * (U) + c0[1] * (V)) * uu +                         \
                    (c0[2] * (U) + c0[3] * (V)) * vv +                         \
                    (c0[4] * uu + c0[5] * uvp + c0[6] * vv) +                  \
                    (c0[7] * (U) + c0[8] * (V) + c0[9]));                      \
        O1 = (V) + ((c1[0] * (U) + c1[1] * (V)) * uu +                         \
                    (c1[2] * (U) + c1[3] * (V)) * vv +                         \
                    (c1[4] * uu + c1[5] * uvp + c1[6] * vv) +                  \
                    (c1[7] * (U) + c1[8] * (V) + c1[9]));                      \
    }
    EVAL_UV(u4.x, v4.x, o0.x, o1.x);
    EVAL_UV(u4.y, v4.y, o0.y, o1.y);
    EVAL_UV(u4.z, v4.z, o0.z, o1.z);
    EVAL_UV(u4.w, v4.w, o0.w, o1.w);
#undef EVAL_UV

    ((float4*)(out + (size_t)(2 * b) * HW))[r4] = o0;
    ((float4*)(out + (size_t)(2 * b + 1) * HW))[r4] = o1;
}

extern "C" void kernel_launch(void* const* d_in, const int* in_sizes, int n_in,
                              void* d_out, int out_size, void* d_ws, size_t ws_size,
                              hipStream_t stream) {
    const float* x = (const float*)d_in[0];
    PercnnW W;
    W.w1u = (const float*)d_in[1];  W.b1u = (const float*)d_in[2];
    W.w2u = (const float*)d_in[3];  W.b2u = (const float*)d_in[4];
    W.w3u = (const float*)d_in[5];  W.b3u = (const float*)d_in[6];
    W.w4u = (const float*)d_in[7];  W.b4u = (const float*)d_in[8];
    W.w1v = (const float*)d_in[9];  W.b1v = (const float*)d_in[10];
    W.w2v = (const float*)d_in[11]; W.b2v = (const float*)d_in[12];
    W.w3v = (const float*)d_in[13]; W.b3v = (const float*)d_in[14];
    W.w4v = (const float*)d_in[15]; W.b4v = (const float*)d_in[16];
    W.w1s = (const float*)d_in[17]; W.b1s = (const float*)d_in[18];
    W.w2s = (const float*)d_in[19]; W.b2s = (const float*)d_in[20];
    W.w3s = (const float*)d_in[21]; W.b3s = (const float*)d_in[22];
    W.w4s = (const float*)d_in[23]; W.b4s = (const float*)d_in[24];
    float* out = (float*)d_out;

    // 2,097,152 float4 groups / 256 = 8192 blocks, exact cover
    percnn_fused_kernel<<<8192, 256, 0, stream>>>(x, W, out);
}